// Round 5
// baseline (231.610 us; speedup 1.0000x reference)
//
#include <hip/hip_runtime.h>

// DynamicRouting (CapsNet) on MI355X — R10: fused kernel with FINE grid
// (480 x 192), f64-atomic G-partials, and a tree grid-barrier.  D=2 dispatches.
// B=16, I=32, C=8, J=10, D=16, H=W=6 -> DHW=576. num_routing=3 (fixed).
//
// Cost model fitted to R5/R8/R9: dur ~= 55us (harness 360MB poison fill)
// + ~15us per dispatch + sum(kernel times).
//   R5: 55+75+49=179   R8: 55+45+117=216   R9: 55+75+79=209  (all match)
// -> levers: dispatch count (R8's fused was right) AND kernel-internal
// parallelism (R9's 480x192 grid was right). R8's fused was slow because of
// 160-block starvation + single-counter barrier (160-way serialization);
// R9's split was slow because 480 blocks redundantly folded a 3x bigger,
// strided Gp set (~118MB of f64 L2 reads).
//
// R10 combines the fixes:
//  - one fused kernel, 480 blocks x 192 thr (24KiB LDS -> 2 blocks/CU
//    co-resident; all 256 CUs busy; co-residency: LDS 2x27KiB<160KiB,
//    6 waves/CU << 32, VGPR ~90 ok -> spin barrier safe);
//  - G partials folded over ck by atomicAdd(double) into a 160x32 table
//    (3-way contention) -> b_ij rebuild reads 41KB/rr per block (R5 cost);
//  - 8-leaf tree barrier: 60 adds/leaf in parallel + 8 root adds, instead
//    of 480 serialized adds on one line; 3 barriers total;
//  - init kernel zeroes the atomic table + barrier state (ws is poisoned).
// All f32 math (s, softmax, squash) is R5/R9-verbatim; only f64 partial
// association changes (~1e-16), which R9 already showed leaves absmax at
// 3.814697e-6. Barrier machinery is R8's (harness-proven, fail-fast guard).

#define NB   16
#define NI   32
#define NC   8
#define NJ   10
#define ND   16
#define NHW  36
#define NDHW 576
#define CK   3                     // dhw chunks
#define CHK  192                   // dhw per chunk (= TPB)
#define NBJ  (NB * NJ)             // 160
#define NBJC (NBJ * CK)            // 480 blocks
#define NTOT  (NB * NJ * NDHW)     // 92160
#define EPSV 1e-7f
#define TPB  192                   // 3 waves
#define NLEAF 8
#define PER_LEAF (NBJC / NLEAF)    // 60
#define BAR_U32 (NLEAF * 32 + 64)  // 8 leaf lines + root line + gen line

static __device__ __forceinline__ double wave_sum(double v) {
    #pragma unroll
    for (int off = 32; off > 0; off >>= 1) v += __shfl_down(v, off);
    return v;
}

// block-reduce |sv| over 192 threads -> slot (thread 0 writes)
static __device__ __forceinline__ void n1_reduce(float sv, double* slot,
                                                 double* nred /*[3]*/) {
    int tid = threadIdx.x;
    double a = wave_sum((double)fabsf(sv));
    if ((tid & 63) == 0) nred[tid >> 6] = a;
    __syncthreads();
    if (tid == 0) slot[0] = (nred[0] + nred[1]) + nred[2];
}

// block-reduce Uv[i]*sv over 192 threads, then ATOMIC ck-fold into gslot[i]
static __device__ __forceinline__ void g_reduce_atomic(const float* Uv, float sv,
                                                       double* gslot,
                                                       double (*gred)[32]) {
    int tid = threadIdx.x, w = tid >> 6, lane = tid & 63;
    #pragma unroll
    for (int i = 0; i < NI; ++i) {
        double p = wave_sum((double)Uv[i] * (double)sv);
        if (lane == 0) gred[w][i] = p;
    }
    __syncthreads();
    if (tid < NI)
        atomicAdd(&gslot[tid], (gred[0][tid] + gred[1][tid]) + gred[2][tid]);
}

// Tree grid-barrier: leaf[blk&7] (own 128B line each) -> root -> gen.
// All 480 blocks co-resident (see header); fail-fast guard, never hangs.
static __device__ __forceinline__ void grid_barrier(unsigned* bar) {
    __syncthreads();                       // block's stores are program-prior
    if (threadIdx.x == 0) {
        __threadfence();                   // agent release: L2 writeback
        unsigned* leaf = &bar[(blockIdx.x & (NLEAF - 1)) * 32];
        unsigned* root = &bar[NLEAF * 32];
        unsigned* gen  = &bar[NLEAF * 32 + 32];
        unsigned g = __hip_atomic_load(gen, __ATOMIC_RELAXED,
                                       __HIP_MEMORY_SCOPE_AGENT);
        unsigned a = __hip_atomic_fetch_add(leaf, 1u, __ATOMIC_ACQ_REL,
                                            __HIP_MEMORY_SCOPE_AGENT);
        if (a == PER_LEAF - 1) {
            __hip_atomic_store(leaf, 0u, __ATOMIC_RELAXED,
                               __HIP_MEMORY_SCOPE_AGENT);
            unsigned r = __hip_atomic_fetch_add(root, 1u, __ATOMIC_ACQ_REL,
                                                __HIP_MEMORY_SCOPE_AGENT);
            if (r == NLEAF - 1) {
                __hip_atomic_store(root, 0u, __ATOMIC_RELAXED,
                                   __HIP_MEMORY_SCOPE_AGENT);
                __hip_atomic_fetch_add(gen, 1u, __ATOMIC_RELEASE,
                                       __HIP_MEMORY_SCOPE_AGENT);
            }
        }
        int guard = 0;
        while (__hip_atomic_load(gen, __ATOMIC_RELAXED,
                                 __HIP_MEMORY_SCOPE_AGENT) == g) {
            __builtin_amdgcn_s_sleep(8);
            if (++guard > (1 << 17)) break;    // ~tens of ms: wrong, not hung
        }
        __threadfence();                   // agent acquire: inv L1 + XCD L2
    }
    __syncthreads();
}

// Zero the atomic G table (2*160*32 doubles) + barrier state (ws is poisoned).
__global__ __launch_bounds__(256) void init_kernel(double* __restrict__ AGp,
                                                   unsigned* __restrict__ bar) {
    int idx = blockIdx.x * 256 + threadIdx.x;
    if (idx < 2 * NBJ * NI) AGp[idx] = 0.0;
    if (idx < BAR_U32) bar[idx] = 0u;
}

// ---------------------------------------------------------------------------
// Fused kernel: one block per (b,j,ck); all 3 routing iterations.
// ---------------------------------------------------------------------------
__global__ __launch_bounds__(TPB) void fused_kernel(
    const float4* __restrict__ uh4, const float* __restrict__ bias,
    double* __restrict__ n1p, double* __restrict__ AGp,
    unsigned* __restrict__ bar, float* __restrict__ out)
{
    __shared__ float4  Utile4[NI * 48];    // 24 KiB chunk tile
    __shared__ double  nred[3];
    __shared__ double  gred[3][32];
    __shared__ double  sc_sh[2][NB];
    __shared__ float   bij_sh[NI * NJ];
    __shared__ float   c_sh[NI];

    const int blk = blockIdx.x;            // (b*NJ + j)*CK + ck
    const int bj = blk / CK, ck = blk - bj * CK;
    const int b = bj / NJ,  j  = bj - b * NJ;
    const int tid = threadIdx.x;

    // ---- phase 1: U[b,:,j,chunk] = sum_c u_hat (R9 a1 verbatim, no U2) ----
    // u_hat float4 index: ((b*NI+i)*NC + c)*1440 + j*144 + ck*48 + f4
    #pragma unroll
    for (int g = 0; g < 8; ++g) {
        int lin = g * TPB + tid;           // < 1536 = 32*48
        int i  = lin / 48, f4 = lin - i * 48;
        const float4* p = uh4 + ((size_t)(b * NI + i) * NC) * 1440
                              + j * 144 + ck * 48 + f4;
        float4 acc = make_float4(0.f, 0.f, 0.f, 0.f);
        #pragma unroll
        for (int c = 0; c < NC; ++c) {
            float4 v = p[(size_t)c * 1440];
            acc.x += v.x; acc.y += v.y; acc.z += v.z; acc.w += v.w;
        }
        Utile4[lin] = acc;
    }
    __syncthreads();

    // ---- lift Uv column into registers; reused by all 3 iterations ----
    const float* Utile = (const float*)Utile4;
    float Uv[NI];
    #pragma unroll
    for (int i = 0; i < NI; ++i) Uv[i] = Utile[i * CHK + tid];
    const float bv = bias[j * ND + (ck * CHK + tid) / NHW];

    // ---- iteration 0 (c = 0.1 exactly) ----
    const float cw = 1.0f / 10.0f;
    float sv = bv;
    #pragma unroll
    for (int i = 0; i < NI; ++i) sv += cw * Uv[i];

    n1_reduce(sv, &n1p[blk], nred);
    g_reduce_atomic(Uv, sv, &AGp[(size_t)bj * NI], gred);
    grid_barrier(bar);

    // ---- iterations 1 and 2 ----
    for (int R = 1; R <= 2; ++R) {
        // sc for each prior iteration (fold j and ck; R9 order)
        if (tid < R * NB) {
            int rr = tid / NB, bb = tid - rr * NB;
            double n1 = 0.0;
            #pragma unroll
            for (int jj = 0; jj < NJ; ++jj)
                #pragma unroll
                for (int cc = 0; cc < CK; ++cc)
                    n1 += n1p[(size_t)rr * NBJC + (bb * NJ + jj) * CK + cc];
            double nsq = n1 * n1;
            sc_sh[rr][bb] = (nsq / (1.0 + nsq)) / (n1 + (double)EPSV);
        }
        __syncthreads();

        // b_ij[i,jj] from the ck-folded atomic table (R5-sized read set)
        for (int e = tid; e < NI * NJ; e += TPB) {
            int i = e / NJ, jj = e - i * NJ;
            double a = 0.0;
            for (int rr = 0; rr < R; ++rr)
                #pragma unroll
                for (int bb = 0; bb < NB; ++bb)
                    a += sc_sh[rr][bb] *
                         AGp[(size_t)rr * (NBJ * NI) +
                             (size_t)(bb * NJ + jj) * NI + i];
            bij_sh[e] = (float)a;
        }
        __syncthreads();

        // softmax rows -> c[:, j]
        if (tid < NI) {
            float m = -1e30f;
            #pragma unroll
            for (int jj = 0; jj < NJ; ++jj) m = fmaxf(m, bij_sh[tid * NJ + jj]);
            float sum = 0.f;
            #pragma unroll
            for (int jj = 0; jj < NJ; ++jj) sum += expf(bij_sh[tid * NJ + jj] - m);
            c_sh[tid] = expf(bij_sh[tid * NJ + j] - m) / sum;
        }
        __syncthreads();

        // s pass from registers
        sv = bv;
        #pragma unroll
        for (int i = 0; i < NI; ++i) sv += c_sh[i] * Uv[i];

        n1_reduce(sv, &n1p[(size_t)R * NBJC + blk], nred);
        if (R == 1)
            g_reduce_atomic(Uv, sv, &AGp[(size_t)(NBJ + bj) * NI], gred);
        grid_barrier(bar);
    }

    // ---- epilogue: v = (n1^2/(1+n1^2)) * (s/(n1+eps)), R9 fold order ----
    if (tid == 0) {
        double n1 = 0.0;
        #pragma unroll
        for (int jj = 0; jj < NJ; ++jj)
            #pragma unroll
            for (int cc = 0; cc < CK; ++cc)
                n1 += n1p[(size_t)2 * NBJC + (b * NJ + jj) * CK + cc];
        nred[0] = n1;
    }
    __syncthreads();
    float n1f = (float)nred[0];
    float nsq = n1f * n1f;
    out[(size_t)bj * NDHW + ck * CHK + tid] =
        (nsq / (1.f + nsq)) * (sv / (n1f + EPSV));
}

extern "C" void kernel_launch(void* const* d_in, const int* in_sizes, int n_in,
                              void* d_out, int out_size, void* d_ws, size_t ws_size,
                              hipStream_t stream)
{
    const float* u_hat = (const float*)d_in[0];
    const float* bias  = (const float*)d_in[1];
    float* out = (float*)d_out;
    // d_in[2] = num_routing, fixed at 3 by the problem.

    // Workspace layout (8B aligned):
    //   n1p : 3*480 doubles   (11,520 B)  per-block, plain writes
    //   AGp : 2*160*32 doubles(81,920 B)  atomic ck-folded G table
    //   bar : BAR_U32 uints   ( 1,280 B)  tree-barrier state
    double*   n1p = (double*)d_ws;
    double*   AGp = n1p + 3 * NBJC;
    unsigned* bar = (unsigned*)(AGp + 2 * NBJ * NI);

    init_kernel<<<(2 * NBJ * NI + 255) / 256, 256, 0, stream>>>(AGp, bar);
    fused_kernel<<<NBJC, TPB, 0, stream>>>(
        (const float4*)u_hat, bias, n1p, AGp, bar, out);
}

// Round 7
// 192.734 us; speedup vs baseline: 1.2017x; 1.2017x over previous
//
#include <hip/hip_runtime.h>

// DynamicRouting (CapsNet) on MI355X — R12: D=3 plain kernels, transposed
// partial layouts (contiguous prologue reads), ab2+v merged into a per-b
// final kernel. No atomics, no spins, no memset — only harness-proven
// mechanisms (R5/R9/R10 all passed with these).
// B=16, I=32, C=8, J=10, D=16, H=W=6 -> DHW=576. num_routing=3 (fixed).
//
// R11 post-mortem: 3rd container death on a new sync topology -> device-side
// grid sync is abandoned; extract wins from the plain pipeline instead.
// Measured model: dur ~= 55us (360MB poison fill) + ~20us/dispatch + kernels.
//   R5 (D=4): kernels ~44us.  R9 (D=4 fine-grid): kernels ~74us, the +30
//   being the ab rebuild reading Gp at 256B stride (1 double per 64B line
//   ~= 1.1GB effective L2 traffic). That's a LAYOUT bug, not geometry.
//
// R12:
//  - Gp_t[rr][j][i][b*CK+ck]: one b_ij entry reads 48 CONTIGUOUS doubles;
//    n1p_t[rr][b][j*CK+ck]: one sc entry reads 30 contiguous doubles.
//    Fold orders (rr outer, bb, cc; jj outer, cc) are R9-verbatim -> f64
//    results bit-identical (R9 passed, absmax 3.814697e-6).
//  - final_kernel (one block per b, 1024 thr): rebuilds c for ALL j,
//    computes s into LDS (23KB), reduces n1 with R9's exact wave/group
//    structure (group g=(jj,cc,w) <-> s_sh[g*64+lane], (w0+w1)+w2, jj-outer
//    cc-inner), squashes, writes out. Replaces ab<2> + v_kernel: one fewer
//    dispatch (~20us) and no s round-trip.

#define NB   16
#define NI   32
#define NC   8
#define NJ   10
#define ND   16
#define NHW  36
#define NDHW 576
#define CK   3                       // dhw chunks
#define CHK  192                     // dhw per chunk (= TPB)
#define NBJ  (NB * NJ)               // 160
#define NBJC (NBJ * CK)              // 480 blocks (a1, ab1)
#define NTOT  (NB * NJ * NDHW)       // 92160
#define EPSV 1e-7f
#define TPB  192                     // 3 waves
#define FTPB 1024                    // final kernel: 16 waves
// transposed partial strides (doubles)
#define GP_ITER (NJ * NI * NB * CK)  // 15360
#define GP_J    (NI * NB * CK)       // 1536
#define GP_I    (NB * CK)            // 48
#define N1_ITER (NB * NJ * CK)       // 480
#define N1_B    (NJ * CK)            // 30

static __device__ __forceinline__ double wave_sum(double v) {
    #pragma unroll
    for (int off = 32; off > 0; off >>= 1) v += __shfl_down(v, off);
    return v;
}

// block-reduce |sv| over 192 threads -> slot (thread 0 writes one double)
static __device__ __forceinline__ void n1_reduce(float sv, double* slot,
                                                 double* nred /*[3]*/) {
    int tid = threadIdx.x;
    double a = wave_sum((double)fabsf(sv));
    if ((tid & 63) == 0) nred[tid >> 6] = a;
    __syncthreads();
    if (tid == 0) slot[0] = (nred[0] + nred[1]) + nred[2];
}

// block-reduce Uv[i]*sv over 192 threads; store to gbase[i*GP_I] (transposed)
static __device__ __forceinline__ void g_reduce_t(const float* Uv, float sv,
                                                  double* gbase,
                                                  double (*gred)[32] /*[3][32]*/) {
    int tid = threadIdx.x, w = tid >> 6, lane = tid & 63;
    #pragma unroll
    for (int i = 0; i < NI; ++i) {
        double p = wave_sum((double)Uv[i] * (double)sv);
        if (lane == 0) gred[w][i] = p;
    }
    __syncthreads();
    if (tid < NI)
        gbase[tid * GP_I] = (gred[0][tid] + gred[1][tid]) + gred[2][tid];
}

// ---------------------------------------------------------------------------
// Kernel A1 = channel-reduce (float4) + routing iteration 0 (c == 0.1).
// Grid 480 x 192; one block per (b,j,ck). R9-verbatim except partial layout.
// ---------------------------------------------------------------------------
__global__ __launch_bounds__(TPB) void a1_kernel(
    const float4* __restrict__ uh4, const float* __restrict__ bias,
    float4* __restrict__ U2f4, double* __restrict__ n1p, double* __restrict__ Gp)
{
    __shared__ float4  Utile4[NI * 48];    // 24 KiB chunk tile
    __shared__ double  nred[3];
    __shared__ double  gred[3][32];

    const int blk = blockIdx.x;            // (b*NJ + j)*CK + ck
    const int bj = blk / CK, ck = blk - bj * CK;
    const int b = bj / NJ,  j  = bj - b * NJ;
    const int tid = threadIdx.x;

    // u_hat float4 index: ((b*NI+i)*NC + c)*1440 + j*144 + ck*48 + f4
    #pragma unroll
    for (int g = 0; g < 8; ++g) {
        int lin = g * TPB + tid;           // < 1536 = 32*48
        int i  = lin / 48, f4 = lin - i * 48;
        const float4* p = uh4 + ((size_t)(b * NI + i) * NC) * 1440
                              + j * 144 + ck * 48 + f4;
        float4 acc = make_float4(0.f, 0.f, 0.f, 0.f);
        #pragma unroll
        for (int c = 0; c < NC; ++c) {
            float4 v = p[(size_t)c * 1440];
            acc.x += v.x; acc.y += v.y; acc.z += v.z; acc.w += v.w;
        }
        Utile4[lin] = acc;
        // U2[b][j][i][dhw] as float4: bj*4608 + i*144 + ck*48 + f4
        U2f4[(size_t)bj * 4608 + i * 144 + ck * 48 + f4] = acc;
    }
    __syncthreads();

    const float* Utile = (const float*)Utile4;
    const float cw = 1.0f / 10.0f;
    float Uv[NI];
    float sv = bias[j * ND + (ck * CHK + tid) / NHW];
    #pragma unroll
    for (int i = 0; i < NI; ++i) {
        Uv[i] = Utile[i * CHK + tid];
        sv += cw * Uv[i];
    }

    n1_reduce(sv, &n1p[b * N1_B + j * CK + ck], nred);
    g_reduce_t(Uv, sv, Gp + j * GP_J + b * CK + ck, gred);
}

// ---------------------------------------------------------------------------
// Kernel AB1 = routing iteration 1. Grid 480 x 192. Prologue rebuilds
// sc/b_ij from iteration-0 partials with CONTIGUOUS reads; same fold orders.
// ---------------------------------------------------------------------------
__global__ __launch_bounds__(TPB) void ab1_kernel(
    const float* __restrict__ U2, const float* __restrict__ bias,
    double* __restrict__ n1p, double* __restrict__ Gp)
{
    __shared__ double sc_sh[NB];
    __shared__ float  bij_sh[NI * NJ];
    __shared__ float  c_sh[NI];
    __shared__ double nred[3];
    __shared__ double gred[3][32];

    const int blk = blockIdx.x;            // (b*NJ + j)*CK + ck
    const int bj = blk / CK, ck = blk - bj * CK;
    const int b = bj / NJ,  j  = bj - b * NJ;
    const int tid = threadIdx.x;

    // sc[bb] from 30 contiguous doubles (jj outer, cc inner — R9 order)
    if (tid < NB) {
        const double* np = n1p + tid * N1_B;
        double n1 = 0.0;
        #pragma unroll
        for (int jj = 0; jj < NJ; ++jj)
            #pragma unroll
            for (int cc = 0; cc < CK; ++cc) n1 += np[jj * CK + cc];
        double nsq = n1 * n1;
        sc_sh[tid] = (nsq / (1.0 + nsq)) / (n1 + (double)EPSV);
    }
    __syncthreads();

    // b_ij[i,jj]: 48 contiguous doubles per entry (bb outer, cc inner)
    for (int e = tid; e < NI * NJ; e += TPB) {
        int i = e / NJ, jj = e - i * NJ;
        const double* g = Gp + jj * GP_J + i * GP_I;
        double a = 0.0;
        #pragma unroll
        for (int bb = 0; bb < NB; ++bb)
            #pragma unroll
            for (int cc = 0; cc < CK; ++cc)
                a += sc_sh[bb] * g[bb * CK + cc];
        bij_sh[e] = (float)a;
    }
    __syncthreads();

    // softmax rows -> c[:, j]
    if (tid < NI) {
        float m = -1e30f;
        #pragma unroll
        for (int jj = 0; jj < NJ; ++jj) m = fmaxf(m, bij_sh[tid * NJ + jj]);
        float sum = 0.f;
        #pragma unroll
        for (int jj = 0; jj < NJ; ++jj) sum += expf(bij_sh[tid * NJ + jj] - m);
        c_sh[tid] = expf(bij_sh[tid * NJ + j] - m) / sum;
    }
    __syncthreads();

    // s pass (chunk of 192 dhw)
    const float* u2b = U2 + (size_t)bj * 18432 + ck * CHK + tid;
    float Uv[NI];
    float sv = bias[j * ND + (ck * CHK + tid) / NHW];
    #pragma unroll
    for (int i = 0; i < NI; ++i) {
        Uv[i] = u2b[i * NDHW];
        sv += c_sh[i] * Uv[i];
    }

    n1_reduce(sv, &n1p[N1_ITER + b * N1_B + j * CK + ck], nred);
    g_reduce_t(Uv, sv, Gp + GP_ITER + j * GP_J + b * CK + ck, gred);
}

// ---------------------------------------------------------------------------
// FINAL kernel = routing iteration 2 + squash + output. One block per b,
// 1024 threads. n1 reduction reproduces R9's exact tree: group g=(jj,cc,w)
// covers s[jj*576 + cc*192 + w*64 + lane]; per (jj,cc): (w0+w1)+w2;
// outer fold jj then cc. All f32 exprs R9-verbatim.
// ---------------------------------------------------------------------------
__global__ __launch_bounds__(FTPB) void final_kernel(
    const float* __restrict__ U2, const float* __restrict__ bias,
    const double* __restrict__ n1p, const double* __restrict__ Gp,
    float* __restrict__ out)
{
    __shared__ float  s_sh[NJ * NDHW];     // 5760 floats = 23 KiB
    __shared__ double gpart[90];
    __shared__ double sc_sh[2][NB];
    __shared__ float  bij_sh[NI * NJ];
    __shared__ float  c_sh[NI * NJ];
    __shared__ double n1_sh;

    const int b = blockIdx.x;
    const int tid = threadIdx.x;

    // sc for iterations 0 and 1 (30 contiguous doubles each; R9 order)
    if (tid < 2 * NB) {
        int rr = tid / NB, bb = tid - rr * NB;
        const double* np = n1p + (size_t)rr * N1_ITER + bb * N1_B;
        double n1 = 0.0;
        #pragma unroll
        for (int jj = 0; jj < NJ; ++jj)
            #pragma unroll
            for (int cc = 0; cc < CK; ++cc) n1 += np[jj * CK + cc];
        double nsq = n1 * n1;
        sc_sh[rr][bb] = (nsq / (1.0 + nsq)) / (n1 + (double)EPSV);
    }
    __syncthreads();

    // b_ij[i,jj] over both iterations (rr outer, bb, cc — R9 ab<2> order)
    if (tid < NI * NJ) {
        int i = tid / NJ, jj = tid - i * NJ;
        double a = 0.0;
        for (int rr = 0; rr < 2; ++rr) {
            const double* g = Gp + (size_t)rr * GP_ITER + jj * GP_J + i * GP_I;
            #pragma unroll
            for (int bb = 0; bb < NB; ++bb)
                #pragma unroll
                for (int cc = 0; cc < CK; ++cc)
                    a += sc_sh[rr][bb] * g[bb * CK + cc];
        }
        bij_sh[tid] = (float)a;
    }
    __syncthreads();

    // softmax: c[i,jj] for ALL jj (same per-row m/sum chains as R9)
    if (tid < NI * NJ) {
        int i = tid / NJ;
        float m = -1e30f;
        #pragma unroll
        for (int j2 = 0; j2 < NJ; ++j2) m = fmaxf(m, bij_sh[i * NJ + j2]);
        float sum = 0.f;
        #pragma unroll
        for (int j2 = 0; j2 < NJ; ++j2) sum += expf(bij_sh[i * NJ + j2] - m);
        c_sh[tid] = expf(bij_sh[tid] - m) / sum;
    }
    __syncthreads();

    // s pass for all (jj,dhw); coalesced per-i columns of U2[b]
    const float* u2b0 = U2 + (size_t)b * (NJ * NI * NDHW);
    for (int e = tid; e < NJ * NDHW; e += FTPB) {
        int jj = e / NDHW, dhw = e - jj * NDHW;
        const float* up = u2b0 + jj * (NI * NDHW) + dhw;
        float sv = bias[jj * ND + dhw / NHW];
        #pragma unroll
        for (int i = 0; i < NI; ++i) sv += c_sh[i * NJ + jj] * up[i * NDHW];
        s_sh[e] = sv;
    }
    __syncthreads();

    // n1: 90 64-lane groups (g*64+lane tiles s linearly = R9's wave split)
    {
        int wv = tid >> 6, lane = tid & 63;
        for (int g = wv; g < 90; g += (FTPB / 64)) {
            double a = wave_sum((double)fabsf(s_sh[g * 64 + lane]));
            if (lane == 0) gpart[g] = a;
        }
    }
    __syncthreads();
    if (tid == 0) {
        double n1 = 0.0;
        #pragma unroll
        for (int jj = 0; jj < NJ; ++jj)
            #pragma unroll
            for (int cc = 0; cc < CK; ++cc) {
                int gg = jj * 9 + cc * 3;
                n1 += (gpart[gg] + gpart[gg + 1]) + gpart[gg + 2];
            }
        n1_sh = n1;
    }
    __syncthreads();

    // squash + store (R9 v_kernel float exprs verbatim)
    float n1f = (float)n1_sh;
    float nsq = n1f * n1f;
    float* ob = out + (size_t)b * (NJ * NDHW);
    for (int e = tid; e < NJ * NDHW; e += FTPB)
        ob[e] = (nsq / (1.f + nsq)) * (s_sh[e] / (n1f + EPSV));
}

extern "C" void kernel_launch(void* const* d_in, const int* in_sizes, int n_in,
                              void* d_out, int out_size, void* d_ws, size_t ws_size,
                              hipStream_t stream)
{
    const float* u_hat = (const float*)d_in[0];
    const float* bias  = (const float*)d_in[1];
    float* out = (float*)d_out;
    // d_in[2] = num_routing, fixed at 3 by the problem.

    // Workspace layout (8B aligned):
    //   U2  : 2,949,120 floats (11.8 MB)   [b][j][i][dhw]
    //   n1p : 2*480 doubles                n1p_t[rr][b][j*CK+ck]
    //   Gp  : 2*15360 doubles (246 KB)     Gp_t[rr][j][i][b*CK+ck]
    // Every slot is written before any read in the same stream order;
    // no location survives across launches -> poison-safe, no init needed.
    float*  U2  = (float*)d_ws;
    double* n1p = (double*)(U2 + (size_t)NB * NJ * NI * NDHW);
    double* Gp  = n1p + 2 * N1_ITER;

    a1_kernel<<<NBJC, TPB, 0, stream>>>(
        (const float4*)u_hat, bias, (float4*)U2, n1p, Gp);
    ab1_kernel<<<NBJC, TPB, 0, stream>>>(U2, bias, n1p, Gp);
    final_kernel<<<NB, FTPB, 0, stream>>>(U2, bias, n1p, Gp, out);
}

// Round 8
// 185.505 us; speedup vs baseline: 1.2485x; 1.0390x over previous
//
#include <hip/hip_runtime.h>

// DynamicRouting (CapsNet) on MI355X — R13: D=3 plain kernels.
// a1/ab1 = R5's proven 160x576 geometry + R12's transposed (contiguous)
// partial layouts; final = 160-block redundant-n1 kernel (fixes R12's
// 16-block starvation). No atomics, no spins, no memset.
// B=16, I=32, C=8, J=10, D=16, H=W=6 -> DHW=576. num_routing=3 (fixed).
//
// R12 post-mortem: fill 55 + ~20/dispatch (fit on R8/R10's measured fused
// kernels) -> R12 kernels ~78us vs R5's ~44. With the Gp stride fixed,
// a1+ab1 ~30 -> the merged per-b final was ~45us: 16 blocks = 16/256 CUs,
// each CU pulling 737KB of U2 through L3 serially. Merging was right;
// shrinking the grid was wrong (same lesson as R8).
//
// R13 final: the only cross-j coupling is the SCALAR n1(b). So run 160
// blocks x 576 thr (full machine): each (b,j) block computes s for ALL 10
// j of its b (737KB L2/L3-resident reads, 320 FMA/thread), reduces n1(b)
// redundantly (bit-identical across the 10 sibling blocks: same inputs,
// same reduction code), squashes, writes only its own j. Per-block critical
// path ~5us instead of ~45.
//
// Numerics: sc / b_ij / softmax / s f32 chains are BIT-IDENTICAL to R5
// (same fold orders: sc jj 0..9; b_ij rr outer, bb 0..15 inner; s i 0..31).
// Only iter-2's n1 f64 association changes (per-thread jj-fold, then
// 9-wave tree) — R9/R12 changed n1 association twice, absmax stayed at
// exactly 3.814697e-06 (f32 error dominates f64 assoc by ~1e10).
// Poison-safe: every ws slot is written before any read in stream order.

#define NB   16
#define NI   32
#define NC   8
#define NJ   10
#define ND   16
#define NHW  36
#define NDHW 576
#define NBJ  (NB * NJ)             // 160
#define NTOT (NB * NJ * NDHW)      // 92160
#define EPSV 1e-7f
#define TPB  576                   // 9 waves; one thread per dhw
// transposed partial strides (doubles)
#define GP_ITER (NJ * NI * NB)     // 5120  Gp_t[rr][j][i][b]
#define GP_J    (NI * NB)          // 512
#define GP_I    (NB)               // 16
#define N1_ITER (NB * NJ)          // 160   n1p_t[rr][b][j]
#define N1_B    (NJ)               // 10

static __device__ __forceinline__ double wave_sum(double v) {
    #pragma unroll
    for (int off = 32; off > 0; off >>= 1) v += __shfl_down(v, off);
    return v;
}

// block-reduce |sv| over 576 threads -> slot (thread 0 writes one double)
static __device__ __forceinline__ void n1_reduce(float sv, double* slot,
                                                 double* nred /*[9]*/) {
    int tid = threadIdx.x;
    double a = wave_sum((double)fabsf(sv));
    if ((tid & 63) == 0) nred[tid >> 6] = a;
    __syncthreads();
    if (tid == 0) {
        double t = nred[0];
        #pragma unroll
        for (int w = 1; w < 9; ++w) t += nred[w];
        *slot = t;
    }
}

// block-reduce Uv[i]*sv over 576 threads; transposed store gbase[i*GP_I]
static __device__ __forceinline__ void g_reduce_t(const float* Uv, float sv,
                                                  double* gbase,
                                                  double (*gred)[32] /*[9][32]*/) {
    int tid = threadIdx.x, w = tid >> 6, lane = tid & 63;
    #pragma unroll
    for (int i = 0; i < NI; ++i) {
        double p = wave_sum((double)Uv[i] * (double)sv);
        if (lane == 0) gred[w][i] = p;
    }
    __syncthreads();
    if (tid < NI) {
        double t = gred[0][tid];
        #pragma unroll
        for (int w2 = 1; w2 < 9; ++w2) t += gred[w2][tid];
        gbase[tid * GP_I] = t;
    }
}

// ---------------------------------------------------------------------------
// Kernel A1 = channel-reduce (float4) + routing iteration 0 (c == 0.1).
// One block per (b,j), 576 threads. R5-verbatim except partial layout.
// ---------------------------------------------------------------------------
__global__ __launch_bounds__(TPB) void a1_kernel(
    const float4* __restrict__ uh4, const float* __restrict__ bias,
    float4* __restrict__ U2f4, double* __restrict__ n1p, double* __restrict__ Gp)
{
    __shared__ float4  Utile4[NI * 144];   // 72 KiB: [i][f4] for this (b,j)
    __shared__ double  nred[9];
    __shared__ double  gred[9][32];

    const int blk = blockIdx.x;            // b*NJ + j
    const int b = blk / NJ, j = blk - b * NJ;
    const int tid = threadIdx.x;           // dhw in phase 2

    // u_hat float4 index: ((b*NI+i)*NC + c)*1440 + j*144 + f4
    #pragma unroll
    for (int g = 0; g < 8; ++g) {
        int lin = g * TPB + tid;           // < 4608 = 32*144
        int i  = lin / 144, f4 = lin - i * 144;
        const float4* p = uh4 + ((size_t)(b * NI + i) * NC) * 1440 + j * 144 + f4;
        float4 acc = make_float4(0.f, 0.f, 0.f, 0.f);
        #pragma unroll
        for (int c = 0; c < NC; ++c) {
            float4 v = p[(size_t)c * 1440];
            acc.x += v.x; acc.y += v.y; acc.z += v.z; acc.w += v.w;
        }
        Utile4[lin] = acc;
        U2f4[(size_t)blk * 4608 + lin] = acc;   // U2[b][j][i][dhw], linear
    }
    __syncthreads();

    // iteration 0 (c = 0.1 exactly)
    const float* Utile = (const float*)Utile4;
    const float cw = 1.0f / 10.0f;
    float Uv[NI];
    float sv = bias[j * ND + tid / NHW];
    #pragma unroll
    for (int i = 0; i < NI; ++i) {
        Uv[i] = Utile[i * NDHW + tid];
        sv += cw * Uv[i];
    }

    n1_reduce(sv, &n1p[b * N1_B + j], nred);
    g_reduce_t(Uv, sv, Gp + j * GP_J + b, gred);
}

// ---------------------------------------------------------------------------
// Kernel AB1 = routing iteration 1. One block per (b,j), 576 threads.
// Prologue rebuilds sc/b_ij from iter-0 partials with CONTIGUOUS reads.
// ---------------------------------------------------------------------------
__global__ __launch_bounds__(TPB) void ab1_kernel(
    const float* __restrict__ U2, const float* __restrict__ bias,
    double* __restrict__ n1p, double* __restrict__ Gp)
{
    __shared__ double sc_sh[NB];
    __shared__ float  bij_sh[NI * NJ];
    __shared__ float  c_sh[NI];
    __shared__ double nred[9];
    __shared__ double gred[9][32];

    const int blk = blockIdx.x;            // b*NJ + j
    const int b = blk / NJ, j = blk - b * NJ;
    const int tid = threadIdx.x;

    // sc[bb]: 10 contiguous doubles (jj 0..9 — R5 order)
    if (tid < NB) {
        const double* np = n1p + tid * N1_B;
        double n1 = 0.0;
        #pragma unroll
        for (int jj = 0; jj < NJ; ++jj) n1 += np[jj];
        double nsq = n1 * n1;
        sc_sh[tid] = (nsq / (1.0 + nsq)) / (n1 + (double)EPSV);
    }
    __syncthreads();

    // b_ij[i,jj]: 16 contiguous doubles per entry (bb 0..15 — R5 order)
    if (tid < NI * NJ) {
        int i = tid / NJ, jj = tid - i * NJ;
        const double* g = Gp + jj * GP_J + i * GP_I;
        double a = 0.0;
        #pragma unroll
        for (int bb = 0; bb < NB; ++bb) a += sc_sh[bb] * g[bb];
        bij_sh[tid] = (float)a;
    }
    __syncthreads();

    // softmax rows -> c[:, j]
    if (tid < NI) {
        float m = -1e30f;
        #pragma unroll
        for (int jj = 0; jj < NJ; ++jj) m = fmaxf(m, bij_sh[tid * NJ + jj]);
        float sum = 0.f;
        #pragma unroll
        for (int jj = 0; jj < NJ; ++jj) sum += expf(bij_sh[tid * NJ + jj] - m);
        c_sh[tid] = expf(bij_sh[tid * NJ + j] - m) / sum;
    }
    __syncthreads();

    // s pass
    const float* u2b = U2 + (size_t)b * (NJ * NI * NDHW) + j * (NI * NDHW) + tid;
    float Uv[NI];
    float sv = bias[j * ND + tid / NHW];
    #pragma unroll
    for (int i = 0; i < NI; ++i) {
        Uv[i] = u2b[i * NDHW];
        sv += c_sh[i] * Uv[i];
    }

    n1_reduce(sv, &n1p[N1_ITER + b * N1_B + j], nred);
    g_reduce_t(Uv, sv, Gp + GP_ITER + j * GP_J + b, gred);
}

// ---------------------------------------------------------------------------
// FINAL kernel = routing iteration 2 + squash + output. One block per (b,j),
// 576 threads — full machine. Each block computes s for ALL 10 jj of its b
// (so n1(b) is available in-block, bit-identical across sibling blocks) and
// writes only its own j. All f32 chains R5-verbatim; only the n1 f64
// association differs (per-thread jj-fold, then 9-wave tree).
// ---------------------------------------------------------------------------
__global__ __launch_bounds__(TPB) void final_kernel(
    const float* __restrict__ U2, const float* __restrict__ bias,
    const double* __restrict__ n1p, const double* __restrict__ Gp,
    float* __restrict__ out)
{
    __shared__ double sc_sh[2][NB];
    __shared__ float  bij_sh[NI * NJ];
    __shared__ float  c_sh[NI * NJ];
    __shared__ double nred[9];
    __shared__ double n1_sh;

    const int blk = blockIdx.x;            // b*NJ + j
    const int b = blk / NJ, j = blk - b * NJ;
    const int tid = threadIdx.x;           // dhw

    // sc for iterations 0 and 1 (10 contiguous doubles each; R5 order)
    if (tid < 2 * NB) {
        int rr = tid >> 4, bb = tid & 15;
        const double* np = n1p + rr * N1_ITER + bb * N1_B;
        double n1 = 0.0;
        #pragma unroll
        for (int jj = 0; jj < NJ; ++jj) n1 += np[jj];
        double nsq = n1 * n1;
        sc_sh[rr][bb] = (nsq / (1.0 + nsq)) / (n1 + (double)EPSV);
    }
    __syncthreads();

    // b_ij[i,jj] over both iterations (rr outer, bb 0..15 — R5 ab<2> order)
    if (tid < NI * NJ) {
        int i = tid / NJ, jj = tid - i * NJ;
        double a = 0.0;
        for (int rr = 0; rr < 2; ++rr) {
            const double* g = Gp + rr * GP_ITER + jj * GP_J + i * GP_I;
            #pragma unroll
            for (int bb = 0; bb < NB; ++bb) a += sc_sh[rr][bb] * g[bb];
        }
        bij_sh[tid] = (float)a;
    }
    __syncthreads();

    // softmax: c[i,jj] for ALL jj (same per-row m/sum chains as R5)
    if (tid < NI * NJ) {
        int i = tid / NJ;
        float m = -1e30f;
        #pragma unroll
        for (int j2 = 0; j2 < NJ; ++j2) m = fmaxf(m, bij_sh[i * NJ + j2]);
        float sum = 0.f;
        #pragma unroll
        for (int j2 = 0; j2 < NJ; ++j2) sum += expf(bij_sh[i * NJ + j2] - m);
        c_sh[tid] = expf(bij_sh[tid] - m) / sum;
    }
    __syncthreads();

    // s for all jj at this thread's dhw; fold |s| locally; keep own j's s.
    const float* ub = U2 + (size_t)b * (NJ * NI * NDHW) + tid;
    const int drow = tid / NHW;
    double t = 0.0;
    float sv_out = 0.f;
    #pragma unroll 1                       // sequential jj: bounded VGPR use
    for (int jj = 0; jj < NJ; ++jj) {
        const float* up = ub + jj * (NI * NDHW);
        float sv = bias[jj * ND + drow];
        #pragma unroll                     // 32 coalesced loads in flight
        for (int i = 0; i < NI; ++i) sv += c_sh[i * NJ + jj] * up[i * NDHW];
        t += (double)fabsf(sv);
        if (jj == j) sv_out = sv;          // predicated, no runtime indexing
    }

    // n1(b): 9-wave tree over per-thread partials (deterministic; identical
    // across the 10 sibling blocks of this b)
    double a = wave_sum(t);
    if ((tid & 63) == 0) nred[tid >> 6] = a;
    __syncthreads();
    if (tid == 0) {
        double n1 = nred[0];
        #pragma unroll
        for (int w = 1; w < 9; ++w) n1 += nred[w];
        n1_sh = n1;
    }
    __syncthreads();

    // squash + store own j (R5 v_kernel float exprs verbatim)
    float n1f = (float)n1_sh;
    float nsq = n1f * n1f;
    out[(size_t)blk * NDHW + tid] = (nsq / (1.f + nsq)) * (sv_out / (n1f + EPSV));
}

extern "C" void kernel_launch(void* const* d_in, const int* in_sizes, int n_in,
                              void* d_out, int out_size, void* d_ws, size_t ws_size,
                              hipStream_t stream)
{
    const float* u_hat = (const float*)d_in[0];
    const float* bias  = (const float*)d_in[1];
    float* out = (float*)d_out;
    // d_in[2] = num_routing, fixed at 3 by the problem.

    // Workspace layout (8B aligned):
    //   U2  : 2,949,120 floats (11.8 MB)   [b][j][i][dhw]
    //   n1p : 2*160 doubles                n1p_t[rr][b][j]
    //   Gp  : 2*5120 doubles (82 KB)       Gp_t[rr][j][i][b]
    float*  U2  = (float*)d_ws;
    double* n1p = (double*)(U2 + (size_t)NB * NJ * NI * NDHW);
    double* Gp  = n1p + 2 * N1_ITER;

    a1_kernel<<<NBJ, TPB, 0, stream>>>(
        (const float4*)u_hat, bias, (float4*)U2, n1p, Gp);
    ab1_kernel<<<NBJ, TPB, 0, stream>>>(U2, bias, n1p, Gp);
    final_kernel<<<NBJ, TPB, 0, stream>>>(U2, bias, n1p, Gp, out);
}

// Round 9
// 181.967 us; speedup vs baseline: 1.2728x; 1.0194x over previous
//
#include <hip/hip_runtime.h>

// DynamicRouting (CapsNet) on MI355X — R14: R13 with ONE change: the final
// kernel's block->(b,j) mapping is XCD-swizzled so the 10 sibling blocks of
// each b (which redundantly re-read the same 737KB U2[b] slice) are
// CO-LOCATED on one XCD, turning cross-XCD L3 fabric traffic into local L2
// hits.
// B=16, I=32, C=8, J=10, D=16, H=W=6 -> DHW=576. num_routing=3 (fixed).
//
// R13 post-mortem: model (fill 55, ~21/dispatch from R8/R10's measured
// fused kernels) -> R13 kernels ~67us = a1 22 + ab1 ~9 + final ~36.
// final's cost is the 10x redundant U2[b] re-read: with blk=b*10+j the
// siblings sit on all 8 XCDs (dispatch is round-robin, XCD = blk % 8), so
// each XCD's private L2 pulls its own copy of U2[b] through L3 (~118MB of
// fabric traffic + latency). Fix: blk = j*16 + b -> sibling ids are
// b, b+16, ..., b+144, all == b (mod 8) -> one XCD hosts all 10 siblings
// (2 b's per XCD = 1.5MB, fits the 4MB L2). U2[b] crosses L3 ONCE per XCD;
// the 10x redundancy becomes L2 hits at ~4.3TB/s per XCD.
// Pure work->block permutation: all arithmetic, fold orders, and output
// addresses bit-identical to R13 (passed, absmax 3.814697e-06). If the %8
// placement assumption is wrong this is perf-neutral, never incorrect.
//
// Everything else is R13-verbatim: D=3 plain kernels, no atomics/spins/
// memsets; a1/ab1 use R5's proven 160x576 geometry with R12's transposed
// (contiguous-read) partial layouts; poison-safe (every ws slot written
// before read in stream order).

#define NB   16
#define NI   32
#define NC   8
#define NJ   10
#define ND   16
#define NHW  36
#define NDHW 576
#define NBJ  (NB * NJ)             // 160
#define NTOT (NB * NJ * NDHW)      // 92160
#define EPSV 1e-7f
#define TPB  576                   // 9 waves; one thread per dhw
// transposed partial strides (doubles)
#define GP_ITER (NJ * NI * NB)     // 5120  Gp_t[rr][j][i][b]
#define GP_J    (NI * NB)          // 512
#define GP_I    (NB)               // 16
#define N1_ITER (NB * NJ)          // 160   n1p_t[rr][b][j]
#define N1_B    (NJ)               // 10

static __device__ __forceinline__ double wave_sum(double v) {
    #pragma unroll
    for (int off = 32; off > 0; off >>= 1) v += __shfl_down(v, off);
    return v;
}

// block-reduce |sv| over 576 threads -> slot (thread 0 writes one double)
static __device__ __forceinline__ void n1_reduce(float sv, double* slot,
                                                 double* nred /*[9]*/) {
    int tid = threadIdx.x;
    double a = wave_sum((double)fabsf(sv));
    if ((tid & 63) == 0) nred[tid >> 6] = a;
    __syncthreads();
    if (tid == 0) {
        double t = nred[0];
        #pragma unroll
        for (int w = 1; w < 9; ++w) t += nred[w];
        *slot = t;
    }
}

// block-reduce Uv[i]*sv over 576 threads; transposed store gbase[i*GP_I]
static __device__ __forceinline__ void g_reduce_t(const float* Uv, float sv,
                                                  double* gbase,
                                                  double (*gred)[32] /*[9][32]*/) {
    int tid = threadIdx.x, w = tid >> 6, lane = tid & 63;
    #pragma unroll
    for (int i = 0; i < NI; ++i) {
        double p = wave_sum((double)Uv[i] * (double)sv);
        if (lane == 0) gred[w][i] = p;
    }
    __syncthreads();
    if (tid < NI) {
        double t = gred[0][tid];
        #pragma unroll
        for (int w2 = 1; w2 < 9; ++w2) t += gred[w2][tid];
        gbase[tid * GP_I] = t;
    }
}

// ---------------------------------------------------------------------------
// Kernel A1 = channel-reduce (float4) + routing iteration 0 (c == 0.1).
// One block per (b,j), 576 threads. R5-verbatim except partial layout.
// ---------------------------------------------------------------------------
__global__ __launch_bounds__(TPB) void a1_kernel(
    const float4* __restrict__ uh4, const float* __restrict__ bias,
    float4* __restrict__ U2f4, double* __restrict__ n1p, double* __restrict__ Gp)
{
    __shared__ float4  Utile4[NI * 144];   // 72 KiB: [i][f4] for this (b,j)
    __shared__ double  nred[9];
    __shared__ double  gred[9][32];

    const int blk = blockIdx.x;            // b*NJ + j
    const int b = blk / NJ, j = blk - b * NJ;
    const int tid = threadIdx.x;           // dhw in phase 2

    // u_hat float4 index: ((b*NI+i)*NC + c)*1440 + j*144 + f4
    #pragma unroll
    for (int g = 0; g < 8; ++g) {
        int lin = g * TPB + tid;           // < 4608 = 32*144
        int i  = lin / 144, f4 = lin - i * 144;
        const float4* p = uh4 + ((size_t)(b * NI + i) * NC) * 1440 + j * 144 + f4;
        float4 acc = make_float4(0.f, 0.f, 0.f, 0.f);
        #pragma unroll
        for (int c = 0; c < NC; ++c) {
            float4 v = p[(size_t)c * 1440];
            acc.x += v.x; acc.y += v.y; acc.z += v.z; acc.w += v.w;
        }
        Utile4[lin] = acc;
        U2f4[(size_t)blk * 4608 + lin] = acc;   // U2[b][j][i][dhw], linear
    }
    __syncthreads();

    // iteration 0 (c = 0.1 exactly)
    const float* Utile = (const float*)Utile4;
    const float cw = 1.0f / 10.0f;
    float Uv[NI];
    float sv = bias[j * ND + tid / NHW];
    #pragma unroll
    for (int i = 0; i < NI; ++i) {
        Uv[i] = Utile[i * NDHW + tid];
        sv += cw * Uv[i];
    }

    n1_reduce(sv, &n1p[b * N1_B + j], nred);
    g_reduce_t(Uv, sv, Gp + j * GP_J + b, gred);
}

// ---------------------------------------------------------------------------
// Kernel AB1 = routing iteration 1. One block per (b,j), 576 threads.
// Prologue rebuilds sc/b_ij from iter-0 partials with CONTIGUOUS reads.
// ---------------------------------------------------------------------------
__global__ __launch_bounds__(TPB) void ab1_kernel(
    const float* __restrict__ U2, const float* __restrict__ bias,
    double* __restrict__ n1p, double* __restrict__ Gp)
{
    __shared__ double sc_sh[NB];
    __shared__ float  bij_sh[NI * NJ];
    __shared__ float  c_sh[NI];
    __shared__ double nred[9];
    __shared__ double gred[9][32];

    const int blk = blockIdx.x;            // b*NJ + j
    const int b = blk / NJ, j = blk - b * NJ;
    const int tid = threadIdx.x;

    // sc[bb]: 10 contiguous doubles (jj 0..9 — R5 order)
    if (tid < NB) {
        const double* np = n1p + tid * N1_B;
        double n1 = 0.0;
        #pragma unroll
        for (int jj = 0; jj < NJ; ++jj) n1 += np[jj];
        double nsq = n1 * n1;
        sc_sh[tid] = (nsq / (1.0 + nsq)) / (n1 + (double)EPSV);
    }
    __syncthreads();

    // b_ij[i,jj]: 16 contiguous doubles per entry (bb 0..15 — R5 order)
    if (tid < NI * NJ) {
        int i = tid / NJ, jj = tid - i * NJ;
        const double* g = Gp + jj * GP_J + i * GP_I;
        double a = 0.0;
        #pragma unroll
        for (int bb = 0; bb < NB; ++bb) a += sc_sh[bb] * g[bb];
        bij_sh[tid] = (float)a;
    }
    __syncthreads();

    // softmax rows -> c[:, j]
    if (tid < NI) {
        float m = -1e30f;
        #pragma unroll
        for (int jj = 0; jj < NJ; ++jj) m = fmaxf(m, bij_sh[tid * NJ + jj]);
        float sum = 0.f;
        #pragma unroll
        for (int jj = 0; jj < NJ; ++jj) sum += expf(bij_sh[tid * NJ + jj] - m);
        c_sh[tid] = expf(bij_sh[tid * NJ + j] - m) / sum;
    }
    __syncthreads();

    // s pass
    const float* u2b = U2 + (size_t)b * (NJ * NI * NDHW) + j * (NI * NDHW) + tid;
    float Uv[NI];
    float sv = bias[j * ND + tid / NHW];
    #pragma unroll
    for (int i = 0; i < NI; ++i) {
        Uv[i] = u2b[i * NDHW];
        sv += c_sh[i] * Uv[i];
    }

    n1_reduce(sv, &n1p[N1_ITER + b * N1_B + j], nred);
    g_reduce_t(Uv, sv, Gp + GP_ITER + j * GP_J + b, gred);
}

// ---------------------------------------------------------------------------
// FINAL kernel = routing iteration 2 + squash + output. 160 blocks x 576.
// XCD-SWIZZLED mapping: blk = j*NB + b  =>  b = blk % 16, j = blk / 16.
// Sibling blocks of one b (j = 0..9) have ids b, b+16, ..., b+144 — all
// congruent to b mod 8 — so round-robin dispatch puts them on ONE XCD and
// their 10x redundant U2[b] reads hit that XCD's L2 instead of crossing L3.
// Each block computes s for ALL 10 jj of its b (n1(b) available in-block,
// bit-identical across siblings) and writes only its own j. All f32 chains
// R5-verbatim; n1 f64 association as in R13 (passed, absmax 3.814697e-06).
// ---------------------------------------------------------------------------
__global__ __launch_bounds__(TPB) void final_kernel(
    const float* __restrict__ U2, const float* __restrict__ bias,
    const double* __restrict__ n1p, const double* __restrict__ Gp,
    float* __restrict__ out)
{
    __shared__ double sc_sh[2][NB];
    __shared__ float  bij_sh[NI * NJ];
    __shared__ float  c_sh[NI * NJ];
    __shared__ double nred[9];
    __shared__ double n1_sh;

    const int blk = blockIdx.x;            // j*NB + b (swizzled)
    const int b = blk & (NB - 1), j = blk >> 4;
    const int tid = threadIdx.x;           // dhw

    // sc for iterations 0 and 1 (10 contiguous doubles each; R5 order)
    if (tid < 2 * NB) {
        int rr = tid >> 4, bb = tid & 15;
        const double* np = n1p + rr * N1_ITER + bb * N1_B;
        double n1 = 0.0;
        #pragma unroll
        for (int jj = 0; jj < NJ; ++jj) n1 += np[jj];
        double nsq = n1 * n1;
        sc_sh[rr][bb] = (nsq / (1.0 + nsq)) / (n1 + (double)EPSV);
    }
    __syncthreads();

    // b_ij[i,jj] over both iterations (rr outer, bb 0..15 — R5 ab<2> order)
    if (tid < NI * NJ) {
        int i = tid / NJ, jj = tid - i * NJ;
        double a = 0.0;
        for (int rr = 0; rr < 2; ++rr) {
            const double* g = Gp + rr * GP_ITER + jj * GP_J + i * GP_I;
            #pragma unroll
            for (int bb = 0; bb < NB; ++bb) a += sc_sh[rr][bb] * g[bb];
        }
        bij_sh[tid] = (float)a;
    }
    __syncthreads();

    // softmax: c[i,jj] for ALL jj (same per-row m/sum chains as R5)
    if (tid < NI * NJ) {
        int i = tid / NJ;
        float m = -1e30f;
        #pragma unroll
        for (int j2 = 0; j2 < NJ; ++j2) m = fmaxf(m, bij_sh[i * NJ + j2]);
        float sum = 0.f;
        #pragma unroll
        for (int j2 = 0; j2 < NJ; ++j2) sum += expf(bij_sh[i * NJ + j2] - m);
        c_sh[tid] = expf(bij_sh[tid] - m) / sum;
    }
    __syncthreads();

    // s for all jj at this thread's dhw; fold |s| locally; keep own j's s.
    const float* ub = U2 + (size_t)b * (NJ * NI * NDHW) + tid;
    const int drow = tid / NHW;
    double t = 0.0;
    float sv_out = 0.f;
    #pragma unroll 1                       // sequential jj: bounded VGPR use
    for (int jj = 0; jj < NJ; ++jj) {
        const float* up = ub + jj * (NI * NDHW);
        float sv = bias[jj * ND + drow];
        #pragma unroll                     // 32 coalesced loads in flight
        for (int i = 0; i < NI; ++i) sv += c_sh[i * NJ + jj] * up[i * NDHW];
        t += (double)fabsf(sv);
        if (jj == j) sv_out = sv;          // predicated, no runtime indexing
    }

    // n1(b): 9-wave tree over per-thread partials (deterministic; identical
    // across the 10 sibling blocks of this b)
    double a = wave_sum(t);
    if ((tid & 63) == 0) nred[tid >> 6] = a;
    __syncthreads();
    if (tid == 0) {
        double n1 = nred[0];
        #pragma unroll
        for (int w = 1; w < 9; ++w) n1 += nred[w];
        n1_sh = n1;
    }
    __syncthreads();

    // squash + store own j (R5 v_kernel float exprs verbatim)
    float n1f = (float)n1_sh;
    float nsq = n1f * n1f;
    out[(size_t)(b * NJ + j) * NDHW + tid] =
        (nsq / (1.f + nsq)) * (sv_out / (n1f + EPSV));
}

extern "C" void kernel_launch(void* const* d_in, const int* in_sizes, int n_in,
                              void* d_out, int out_size, void* d_ws, size_t ws_size,
                              hipStream_t stream)
{
    const float* u_hat = (const float*)d_in[0];
    const float* bias  = (const float*)d_in[1];
    float* out = (float*)d_out;
    // d_in[2] = num_routing, fixed at 3 by the problem.

    // Workspace layout (8B aligned):
    //   U2  : 2,949,120 floats (11.8 MB)   [b][j][i][dhw]
    //   n1p : 2*160 doubles                n1p_t[rr][b][j]
    //   Gp  : 2*5120 doubles (82 KB)       Gp_t[rr][j][i][b]
    float*  U2  = (float*)d_ws;
    double* n1p = (double*)(U2 + (size_t)NB * NJ * NI * NDHW);
    double* Gp  = n1p + 2 * N1_ITER;

    a1_kernel<<<NBJ, TPB, 0, stream>>>(
        (const float4*)u_hat, bias, (float4*)U2, n1p, Gp);
    ab1_kernel<<<NBJ, TPB, 0, stream>>>(U2, bias, n1p, Gp);
    final_kernel<<<NBJ, TPB, 0, stream>>>(U2, bias, n1p, Gp, out);
}

// Round 10
// 180.556 us; speedup vs baseline: 1.2828x; 1.0078x over previous
//
#include <hip/hip_runtime.h>

// DynamicRouting (CapsNet) on MI355X — R15: R14 with ONE change: a1's load
// phase is restructured for load-level parallelism (16 float4 loads in
// flight per thread instead of ~2).
// B=16, I=32, C=8, J=10, D=16, H=W=6 -> DHW=576. num_routing=3 (fixed).
//
// R14 post-mortem (first round with a real kernel in top-5): a1 = 55.2us,
// hbm 10.7%, VALUBusy 2.4%, occupancy 14.4%, VGPR=48. The 8-channel loads
// sit 23KB apart (each needs its own 64b address); at VGPR=48 the compiler
// keeps ~2 loads in flight and serializes issue->wait->accumulate. Little's
// law: 590KB/CU / 55us = 10.7 GB/s/CU ~ 0.7 loads/thread in flight. Pure
// latency-bound. Fix: explicit load-all-8-then-sum over TWO g-tiles per
// iteration (16 independent global_load_dwordx4 before the first waitcnt)
// + __launch_bounds__(576,2) to raise the VGPR cap to 256.
// f32 accumulation order unchanged (0 + c0 + c1 ... componentwise,
// left-to-right) -> bit-identical to R14 (passed, absmax 3.814697e-06).
//
// Everything else R14-verbatim: D=3 plain kernels; transposed contiguous
// partial layouts; final kernel XCD-swizzled (blk = j*16+b co-locates the
// 10 sibling blocks of each b on one XCD so the 10x redundant U2[b] read
// hits local L2). No atomics, no spins, no memsets; poison-safe.

#define NB   16
#define NI   32
#define NC   8
#define NJ   10
#define ND   16
#define NHW  36
#define NDHW 576
#define NBJ  (NB * NJ)             // 160
#define NTOT (NB * NJ * NDHW)      // 92160
#define EPSV 1e-7f
#define TPB  576                   // 9 waves; one thread per dhw
// transposed partial strides (doubles)
#define GP_ITER (NJ * NI * NB)     // 5120  Gp_t[rr][j][i][b]
#define GP_J    (NI * NB)          // 512
#define GP_I    (NB)               // 16
#define N1_ITER (NB * NJ)          // 160   n1p_t[rr][b][j]
#define N1_B    (NJ)               // 10

static __device__ __forceinline__ double wave_sum(double v) {
    #pragma unroll
    for (int off = 32; off > 0; off >>= 1) v += __shfl_down(v, off);
    return v;
}

// block-reduce |sv| over 576 threads -> slot (thread 0 writes one double)
static __device__ __forceinline__ void n1_reduce(float sv, double* slot,
                                                 double* nred /*[9]*/) {
    int tid = threadIdx.x;
    double a = wave_sum((double)fabsf(sv));
    if ((tid & 63) == 0) nred[tid >> 6] = a;
    __syncthreads();
    if (tid == 0) {
        double t = nred[0];
        #pragma unroll
        for (int w = 1; w < 9; ++w) t += nred[w];
        *slot = t;
    }
}

// block-reduce Uv[i]*sv over 576 threads; transposed store gbase[i*GP_I]
static __device__ __forceinline__ void g_reduce_t(const float* Uv, float sv,
                                                  double* gbase,
                                                  double (*gred)[32] /*[9][32]*/) {
    int tid = threadIdx.x, w = tid >> 6, lane = tid & 63;
    #pragma unroll
    for (int i = 0; i < NI; ++i) {
        double p = wave_sum((double)Uv[i] * (double)sv);
        if (lane == 0) gred[w][i] = p;
    }
    __syncthreads();
    if (tid < NI) {
        double t = gred[0][tid];
        #pragma unroll
        for (int w2 = 1; w2 < 9; ++w2) t += gred[w2][tid];
        gbase[tid * GP_I] = t;
    }
}

// ---------------------------------------------------------------------------
// Kernel A1 = channel-reduce (ILP-batched float4) + routing iteration 0.
// One block per (b,j), 576 threads, min 2 waves/EU (VGPR cap 256).
// Load phase: 2 g-tiles x 8 channels = 16 independent loads in flight,
// then summed in the ORIGINAL order (c=0..7, componentwise).
// ---------------------------------------------------------------------------
__global__ __launch_bounds__(TPB, 2) void a1_kernel(
    const float4* __restrict__ uh4, const float* __restrict__ bias,
    float4* __restrict__ U2f4, double* __restrict__ n1p, double* __restrict__ Gp)
{
    __shared__ float4  Utile4[NI * 144];   // 72 KiB: [i][f4] for this (b,j)
    __shared__ double  nred[9];
    __shared__ double  gred[9][32];

    const int blk = blockIdx.x;            // b*NJ + j
    const int b = blk / NJ, j = blk - b * NJ;
    const int tid = threadIdx.x;           // dhw in phase 2

    // u_hat float4 index: ((b*NI+i)*NC + c)*1440 + j*144 + f4
    #pragma unroll
    for (int g = 0; g < 8; g += 2) {
        int lin0 = g * TPB + tid;          // < 4608 = 32*144
        int lin1 = lin0 + TPB;
        int i0 = lin0 / 144, f40 = lin0 - i0 * 144;
        int i1 = lin1 / 144, f41 = lin1 - i1 * 144;
        const float4* p0 = uh4 + ((size_t)(b * NI + i0) * NC) * 1440 + j * 144 + f40;
        const float4* p1 = uh4 + ((size_t)(b * NI + i1) * NC) * 1440 + j * 144 + f41;

        float4 v0[NC], v1[NC];
        #pragma unroll
        for (int c = 0; c < NC; ++c) v0[c] = p0[(size_t)c * 1440];
        #pragma unroll
        for (int c = 0; c < NC; ++c) v1[c] = p1[(size_t)c * 1440];

        float4 a0 = make_float4(0.f, 0.f, 0.f, 0.f);
        float4 a1 = make_float4(0.f, 0.f, 0.f, 0.f);
        #pragma unroll
        for (int c = 0; c < NC; ++c) {     // same left-to-right chain as R14
            a0.x += v0[c].x; a0.y += v0[c].y; a0.z += v0[c].z; a0.w += v0[c].w;
            a1.x += v1[c].x; a1.y += v1[c].y; a1.z += v1[c].z; a1.w += v1[c].w;
        }
        Utile4[lin0] = a0;
        Utile4[lin1] = a1;
        U2f4[(size_t)blk * 4608 + lin0] = a0;   // U2[b][j][i][dhw], linear
        U2f4[(size_t)blk * 4608 + lin1] = a1;
    }
    __syncthreads();

    // iteration 0 (c = 0.1 exactly)
    const float* Utile = (const float*)Utile4;
    const float cw = 1.0f / 10.0f;
    float Uv[NI];
    float sv = bias[j * ND + tid / NHW];
    #pragma unroll
    for (int i = 0; i < NI; ++i) {
        Uv[i] = Utile[i * NDHW + tid];
        sv += cw * Uv[i];
    }

    n1_reduce(sv, &n1p[b * N1_B + j], nred);
    g_reduce_t(Uv, sv, Gp + j * GP_J + b, gred);
}

// ---------------------------------------------------------------------------
// Kernel AB1 = routing iteration 1. One block per (b,j), 576 threads.
// Prologue rebuilds sc/b_ij from iter-0 partials with CONTIGUOUS reads.
// ---------------------------------------------------------------------------
__global__ __launch_bounds__(TPB) void ab1_kernel(
    const float* __restrict__ U2, const float* __restrict__ bias,
    double* __restrict__ n1p, double* __restrict__ Gp)
{
    __shared__ double sc_sh[NB];
    __shared__ float  bij_sh[NI * NJ];
    __shared__ float  c_sh[NI];
    __shared__ double nred[9];
    __shared__ double gred[9][32];

    const int blk = blockIdx.x;            // b*NJ + j
    const int b = blk / NJ, j = blk - b * NJ;
    const int tid = threadIdx.x;

    // sc[bb]: 10 contiguous doubles (jj 0..9 — R5 order)
    if (tid < NB) {
        const double* np = n1p + tid * N1_B;
        double n1 = 0.0;
        #pragma unroll
        for (int jj = 0; jj < NJ; ++jj) n1 += np[jj];
        double nsq = n1 * n1;
        sc_sh[tid] = (nsq / (1.0 + nsq)) / (n1 + (double)EPSV);
    }
    __syncthreads();

    // b_ij[i,jj]: 16 contiguous doubles per entry (bb 0..15 — R5 order)
    if (tid < NI * NJ) {
        int i = tid / NJ, jj = tid - i * NJ;
        const double* g = Gp + jj * GP_J + i * GP_I;
        double a = 0.0;
        #pragma unroll
        for (int bb = 0; bb < NB; ++bb) a += sc_sh[bb] * g[bb];
        bij_sh[tid] = (float)a;
    }
    __syncthreads();

    // softmax rows -> c[:, j]
    if (tid < NI) {
        float m = -1e30f;
        #pragma unroll
        for (int jj = 0; jj < NJ; ++jj) m = fmaxf(m, bij_sh[tid * NJ + jj]);
        float sum = 0.f;
        #pragma unroll
        for (int jj = 0; jj < NJ; ++jj) sum += expf(bij_sh[tid * NJ + jj] - m);
        c_sh[tid] = expf(bij_sh[tid * NJ + j] - m) / sum;
    }
    __syncthreads();

    // s pass
    const float* u2b = U2 + (size_t)b * (NJ * NI * NDHW) + j * (NI * NDHW) + tid;
    float Uv[NI];
    float sv = bias[j * ND + tid / NHW];
    #pragma unroll
    for (int i = 0; i < NI; ++i) {
        Uv[i] = u2b[i * NDHW];
        sv += c_sh[i] * Uv[i];
    }

    n1_reduce(sv, &n1p[N1_ITER + b * N1_B + j], nred);
    g_reduce_t(Uv, sv, Gp + GP_ITER + j * GP_J + b, gred);
}

// ---------------------------------------------------------------------------
// FINAL kernel = routing iteration 2 + squash + output. 160 blocks x 576.
// XCD-SWIZZLED mapping: blk = j*NB + b  =>  b = blk % 16, j = blk / 16.
// Sibling blocks of one b (j = 0..9) are congruent mod 8 -> one XCD hosts
// all 10, so the 10x redundant U2[b] read stays in that XCD's L2.
// Each block computes s for ALL 10 jj of its b (n1(b) available in-block,
// bit-identical across siblings) and writes only its own j.
// ---------------------------------------------------------------------------
__global__ __launch_bounds__(TPB) void final_kernel(
    const float* __restrict__ U2, const float* __restrict__ bias,
    const double* __restrict__ n1p, const double* __restrict__ Gp,
    float* __restrict__ out)
{
    __shared__ double sc_sh[2][NB];
    __shared__ float  bij_sh[NI * NJ];
    __shared__ float  c_sh[NI * NJ];
    __shared__ double nred[9];
    __shared__ double n1_sh;

    const int blk = blockIdx.x;            // j*NB + b (swizzled)
    const int b = blk & (NB - 1), j = blk >> 4;
    const int tid = threadIdx.x;           // dhw

    // sc for iterations 0 and 1 (10 contiguous doubles each; R5 order)
    if (tid < 2 * NB) {
        int rr = tid >> 4, bb = tid & 15;
        const double* np = n1p + rr * N1_ITER + bb * N1_B;
        double n1 = 0.0;
        #pragma unroll
        for (int jj = 0; jj < NJ; ++jj) n1 += np[jj];
        double nsq = n1 * n1;
        sc_sh[rr][bb] = (nsq / (1.0 + nsq)) / (n1 + (double)EPSV);
    }
    __syncthreads();

    // b_ij[i,jj] over both iterations (rr outer, bb 0..15 — R5 ab<2> order)
    if (tid < NI * NJ) {
        int i = tid / NJ, jj = tid - i * NJ;
        double a = 0.0;
        for (int rr = 0; rr < 2; ++rr) {
            const double* g = Gp + rr * GP_ITER + jj * GP_J + i * GP_I;
            #pragma unroll
            for (int bb = 0; bb < NB; ++bb) a += sc_sh[rr][bb] * g[bb];
        }
        bij_sh[tid] = (float)a;
    }
    __syncthreads();

    // softmax: c[i,jj] for ALL jj (same per-row m/sum chains as R5)
    if (tid < NI * NJ) {
        int i = tid / NJ;
        float m = -1e30f;
        #pragma unroll
        for (int j2 = 0; j2 < NJ; ++j2) m = fmaxf(m, bij_sh[i * NJ + j2]);
        float sum = 0.f;
        #pragma unroll
        for (int j2 = 0; j2 < NJ; ++j2) sum += expf(bij_sh[i * NJ + j2] - m);
        c_sh[tid] = expf(bij_sh[tid] - m) / sum;
    }
    __syncthreads();

    // s for all jj at this thread's dhw; fold |s| locally; keep own j's s.
    const float* ub = U2 + (size_t)b * (NJ * NI * NDHW) + tid;
    const int drow = tid / NHW;
    double t = 0.0;
    float sv_out = 0.f;
    #pragma unroll 1                       // sequential jj: bounded VGPR use
    for (int jj = 0; jj < NJ; ++jj) {
        const float* up = ub + jj * (NI * NDHW);
        float sv = bias[jj * ND + drow];
        #pragma unroll                     // 32 coalesced loads in flight
        for (int i = 0; i < NI; ++i) sv += c_sh[i * NJ + jj] * up[i * NDHW];
        t += (double)fabsf(sv);
        if (jj == j) sv_out = sv;          // predicated, no runtime indexing
    }

    // n1(b): 9-wave tree over per-thread partials (deterministic; identical
    // across the 10 sibling blocks of this b)
    double a = wave_sum(t);
    if ((tid & 63) == 0) nred[tid >> 6] = a;
    __syncthreads();
    if (tid == 0) {
        double n1 = nred[0];
        #pragma unroll
        for (int w = 1; w < 9; ++w) n1 += nred[w];
        n1_sh = n1;
    }
    __syncthreads();

    // squash + store own j (R5 v_kernel float exprs verbatim)
    float n1f = (float)n1_sh;
    float nsq = n1f * n1f;
    out[(size_t)(b * NJ + j) * NDHW + tid] =
        (nsq / (1.f + nsq)) * (sv_out / (n1f + EPSV));
}

extern "C" void kernel_launch(void* const* d_in, const int* in_sizes, int n_in,
                              void* d_out, int out_size, void* d_ws, size_t ws_size,
                              hipStream_t stream)
{
    const float* u_hat = (const float*)d_in[0];
    const float* bias  = (const float*)d_in[1];
    float* out = (float*)d_out;
    // d_in[2] = num_routing, fixed at 3 by the problem.

    // Workspace layout (8B aligned):
    //   U2  : 2,949,120 floats (11.8 MB)   [b][j][i][dhw]
    //   n1p : 2*160 doubles                n1p_t[rr][b][j]
    //   Gp  : 2*5120 doubles (82 KB)       Gp_t[rr][j][i][b]
    float*  U2  = (float*)d_ws;
    double* n1p = (double*)(U2 + (size_t)NB * NJ * NI * NDHW);
    double* Gp  = n1p + 2 * N1_ITER;

    a1_kernel<<<NBJ, TPB, 0, stream>>>(
        (const float4*)u_hat, bias, (float4*)U2, n1p, Gp);
    ab1_kernel<<<NBJ, TPB, 0, stream>>>(U2, bias, n1p, Gp);
    final_kernel<<<NBJ, TPB, 0, stream>>>(U2, bias, n1p, Gp, out);
}